// Round 1
// baseline (2659.630 us; speedup 1.0000x reference)
//
#include <hip/hip_runtime.h>
#include <cstdint>
#include <cstddef>

#define B_ 128
#define T_ 500
#define I_ 512
#define H_ 1024
#define O_ 11
#define BETA 0.9f
#define THRESH 1.0f

typedef __attribute__((ext_vector_type(4))) float f32x4;
typedef __attribute__((ext_vector_type(8))) short bf16x8;
typedef __attribute__((ext_vector_type(4))) unsigned int u32x4;

__device__ __forceinline__ unsigned short bf16_rne(float f) {
  unsigned int u = __float_as_uint(f);
  unsigned int r = u + 0x7FFFu + ((u >> 16) & 1u);
  return (unsigned short)(r >> 16);
}
__device__ __forceinline__ float bf16_to_f(unsigned short h) {
  return __uint_as_float(((unsigned int)h) << 16);
}

// ---------------- Wt2 [1024][2048] bf16: k2 = 4*i + c, c in {0,1}->hi(W_in[i][n]), {2,3}->lo ----
__global__ void k_build_wt(const float* __restrict__ W_in, unsigned short* __restrict__ Wt) {
  int n = blockIdx.y;
  int k2 = blockIdx.x * 256 + threadIdx.x;  // 0..2047
  int i = k2 >> 2;
  float w = W_in[i * H_ + n];
  unsigned short hi = bf16_rne(w);
  unsigned short v = (k2 & 2) ? bf16_rne(w - bf16_to_f(hi)) : hi;
  Wt[(size_t)n * 2048 + k2] = v;
}

// ---------------- CSC build (deterministic, two-pass, k-ascending order) ----------------------
__global__ void k_csc_count(const float* __restrict__ mask, unsigned int* __restrict__ cntkc) {
  int id = blockIdx.x * 256 + threadIdx.x;  // 16384 threads
  int h = id & (H_ - 1);
  int kc = id >> 10;                         // 0..15
  unsigned c = 0;
  for (int k = kc * 64; k < kc * 64 + 64; ++k) c += (mask[(size_t)k * H_ + h] != 0.f);
  cntkc[kc * H_ + h] = c;
}

__global__ void k_csc_fill(const float* __restrict__ W_rec, const float* __restrict__ mask,
                           const unsigned int* __restrict__ cntkc,
                           unsigned int* __restrict__ csc, unsigned int* __restrict__ colcnt) {
  int id = blockIdx.x * 256 + threadIdx.x;
  int h = id & (H_ - 1);
  int kc = id >> 10;
  unsigned off = 0;
  for (int p = 0; p < kc; ++p) off += cntkc[p * H_ + h];
  for (int k = kc * 64; k < kc * 64 + 64; ++k) {
    float m = mask[(size_t)k * H_ + h];
    if (m != 0.f) {
      float w = W_rec[(size_t)k * H_ + h] * m;
      unsigned int wb = __float_as_uint(w);
      unsigned int pk = ((wb + 512u) & 0xFFFFFC00u) | (unsigned)k;  // RNE into low-10 idx bits
      if (off < 128u) csc[(size_t)off * H_ + h] = pk;
      off++;
    }
  }
  if (kc == 15) colcnt[h] = off < 128u ? off : 128u;
}

// zero-pad each column up to its 64-column group's max count; record group max
__global__ void k_csc_pad(unsigned int* __restrict__ csc, const unsigned int* __restrict__ colcnt,
                          unsigned int* __restrict__ gmax) {
  __shared__ unsigned int sm[H_];
  int h = threadIdx.x;
  unsigned c = colcnt[h];
  sm[h] = c;
  __syncthreads();
  int g = h >> 6;
  unsigned m = 0;
  for (int j = 0; j < 64; ++j) m = m > sm[g * 64 + j] ? m : sm[g * 64 + j];
  if ((h & 63) == 0) gmax[g] = m;
  for (unsigned j = c; j < m; ++j) csc[(size_t)j * H_ + h] = 0u;  // w=+0, idx=0 -> adds 0
}

// ---------------- xs2 chunk [128*Tc][2048] bf16: 4 bf16 per f32: {hi,lo,hi,lo} ----------------
__global__ void k_build_xs(const float* __restrict__ x, unsigned short* __restrict__ xs,
                           int t0, int Tc) {
  int id = blockIdx.x * 256 + threadIdx.x;  // one thread = 4 consecutive f32
  int rr = id >> 7;                          // 128 quads per row (512/4)
  int q = id & 127;
  int b = rr / Tc, tt = rr % Tc;
  const float4 v = *(const float4*)&x[((size_t)(b * T_ + t0 + tt)) * I_ + q * 4];
  alignas(16) unsigned short o[16];
  float vv[4] = {v.x, v.y, v.z, v.w};
#pragma unroll
  for (int j = 0; j < 4; ++j) {
    unsigned short hi = bf16_rne(vv[j]);
    unsigned short lo = bf16_rne(vv[j] - bf16_to_f(hi));
    o[4 * j + 0] = hi; o[4 * j + 1] = lo; o[4 * j + 2] = hi; o[4 * j + 3] = lo;
  }
  *(u32x4*)&xs[(size_t)rr * 2048 + q * 16] = *(u32x4*)o;
  *(u32x4*)&xs[(size_t)rr * 2048 + q * 16 + 8] = *(u32x4*)(o + 8);
}

// ---------------- split-bf16 GEMM: drive[rr][n] = xs2[rr][:] . Wt2[n][:], K2=2048 -------------
#define LDA 72  // padded LDS stride (elems) -> 2-way-free bank pattern
__global__ __launch_bounds__(512, 1) void k_gemm(const unsigned short* __restrict__ xs,
                                                 const unsigned short* __restrict__ Wt,
                                                 float* __restrict__ drive) {
  __shared__ __align__(16) unsigned short As[128 * LDA];
  __shared__ __align__(16) unsigned short Bs[256 * LDA];
  int mt = blockIdx.x, nt = blockIdx.y;
  int tid = threadIdx.x;
  int lane = tid & 63, w = tid >> 6;
  int wr = w >> 2, wc = w & 3;  // 2 x 4 wave grid, each wave 64x64
  f32x4 acc[4][4] = {};
  int arow = tid >> 2, aq = tid & 3;   // A stage: 128 rows x 4 quarters(16 elems)
  int brow = tid >> 1, bh = tid & 1;   // B stage: 256 rows x 2 halves(32 elems)
  const unsigned short* xsrow = xs + (size_t)(mt * 128 + arow) * 2048 + aq * 16;
  const unsigned short* wtrow = Wt + (size_t)(nt * 256 + brow) * 2048 + bh * 32;
  for (int kt = 0; kt < 32; ++kt) {
    u32x4 a0 = *(const u32x4*)(xsrow + kt * 64);
    u32x4 a1 = *(const u32x4*)(xsrow + kt * 64 + 8);
    u32x4 b0 = *(const u32x4*)(wtrow + kt * 64);
    u32x4 b1 = *(const u32x4*)(wtrow + kt * 64 + 8);
    u32x4 b2 = *(const u32x4*)(wtrow + kt * 64 + 16);
    u32x4 b3 = *(const u32x4*)(wtrow + kt * 64 + 24);
    __syncthreads();  // previous iter's LDS reads done
    *(u32x4*)&As[arow * LDA + aq * 16] = a0;
    *(u32x4*)&As[arow * LDA + aq * 16 + 8] = a1;
    *(u32x4*)&Bs[brow * LDA + bh * 32] = b0;
    *(u32x4*)&Bs[brow * LDA + bh * 32 + 8] = b1;
    *(u32x4*)&Bs[brow * LDA + bh * 32 + 16] = b2;
    *(u32x4*)&Bs[brow * LDA + bh * 32 + 24] = b3;
    __syncthreads();
#pragma unroll
    for (int kk = 0; kk < 2; ++kk) {
      bf16x8 af[4], bf[4];
#pragma unroll
      for (int mi = 0; mi < 4; ++mi)
        af[mi] = *(const bf16x8*)&As[(wr * 64 + mi * 16 + (lane & 15)) * LDA + kk * 32 + (lane >> 4) * 8];
#pragma unroll
      for (int ni = 0; ni < 4; ++ni)
        bf[ni] = *(const bf16x8*)&Bs[(wc * 64 + ni * 16 + (lane & 15)) * LDA + kk * 32 + (lane >> 4) * 8];
#pragma unroll
      for (int mi = 0; mi < 4; ++mi)
#pragma unroll
        for (int ni = 0; ni < 4; ++ni)
          acc[mi][ni] = __builtin_amdgcn_mfma_f32_16x16x32_bf16(af[mi], bf[ni], acc[mi][ni], 0, 0, 0);
    }
  }
  int r0 = (lane >> 4) * 4, c0 = lane & 15;
#pragma unroll
  for (int mi = 0; mi < 4; ++mi) {
    int rowb = mt * 128 + wr * 64 + mi * 16 + r0;
#pragma unroll
    for (int ni = 0; ni < 4; ++ni) {
      int col = nt * 256 + wc * 64 + ni * 16 + c0;
#pragma unroll
      for (int r = 0; r < 4; ++r)
        drive[(size_t)(rowb + r) * H_ + col] = acc[mi][ni][r];
    }
  }
}

// ---------------- recurrent scan: one WG (1024 thr) per batch element -------------------------
__global__ __launch_bounds__(1024, 1) void k_rsnn(
    const float* __restrict__ drive, const unsigned int* __restrict__ csc,
    const unsigned int* __restrict__ gmax_arr,
    const float* __restrict__ h_bias, const float* __restrict__ W_out,
    const float* __restrict__ b_out,
    float* __restrict__ state_v, float* __restrict__ state_s, float* __restrict__ state_c,
    float* __restrict__ out, int t0, int Tc, int last) {
  __shared__ float sbuf[2][H_];
  __shared__ float red[H_];
  __shared__ float part[352];
  int h = threadIdx.x;
  int b = blockIdx.x;
  float bias = h_bias[h];
  int jmax = (int)gmax_arr[h >> 6];  // wave-uniform loop bound (padded columns)
  float v, s, cnt;
  if (t0 == 0) { v = 0.f; s = 0.f; cnt = 0.f; }
  else { v = state_v[b * H_ + h]; s = state_s[b * H_ + h]; cnt = state_c[b * H_ + h]; }
  int cur = 0;
  sbuf[0][h] = s;
  __syncthreads();
  const float* dptr = drive + (size_t)b * Tc * H_ + h;
  for (int t = 0; t < Tc; ++t) {
    float d = dptr[(size_t)t * H_];  // issued early, latency hidden by CSC loop
    float rec = 0.f;
    const float* sb = sbuf[cur];
#pragma unroll 4
    for (int j = 0; j < jmax; ++j) {
      unsigned e = csc[(size_t)j * H_ + h];
      rec += __uint_as_float(e & 0xFFFFFC00u) * sb[e & 1023u];
    }
    v = BETA * v + (d + bias) + rec;
    float sn = (v - THRESH) > 0.f ? 1.f : 0.f;
    v -= sn * THRESH;
    cnt += sn;
    sbuf[cur ^ 1][h] = sn;
    s = sn;
    __syncthreads();
    cur ^= 1;
  }
  if (!last) {
    state_v[b * H_ + h] = v; state_s[b * H_ + h] = s; state_c[b * H_ + h] = cnt;
  } else {
    red[h] = cnt;
    __syncthreads();
    if (h < 352) {                    // 11 outputs x 32 segments
      int o = h >> 5, seg = h & 31;
      float p = 0.f;
      for (int j = 0; j < 32; ++j) {
        int hh = seg * 32 + j;
        p += red[hh] * W_out[hh * O_ + o];
      }
      part[h] = p;
    }
    __syncthreads();
    if (h < O_) {
      float sum = 0.f;
      for (int g = 0; g < 32; ++g) sum += part[(h << 5) + g];
      out[b * O_ + h] = b_out[h] + sum * (1.0f / (float)T_);
    }
  }
}

extern "C" void kernel_launch(void* const* d_in, const int* in_sizes, int n_in,
                              void* d_out, int out_size, void* d_ws, size_t ws_size,
                              hipStream_t stream) {
  (void)in_sizes; (void)n_in; (void)out_size;
  const float* x = (const float*)d_in[0];
  const float* W_in = (const float*)d_in[1];
  const float* W_rec = (const float*)d_in[2];
  const float* W_out = (const float*)d_in[3];
  const float* h_bias = (const float*)d_in[4];
  const float* b_out = (const float*)d_in[5];
  const float* mask = (const float*)d_in[6];
  float* out = (float*)d_out;

  char* ws = (char*)d_ws;
  size_t off = 0;
  auto alloc = [&](size_t bytes) {
    void* p = ws + off;
    off = (off + bytes + 255) & ~(size_t)255;
    return p;
  };
  unsigned short* Wt = (unsigned short*)alloc((size_t)H_ * 2048 * 2);
  unsigned int* csc = (unsigned int*)alloc((size_t)128 * H_ * 4);
  unsigned int* colcnt = (unsigned int*)alloc((size_t)H_ * 4);
  unsigned int* cntkc = (unsigned int*)alloc((size_t)16 * H_ * 4);
  unsigned int* gmaxb = (unsigned int*)alloc((size_t)16 * 4);
  float* st_v = (float*)alloc((size_t)B_ * H_ * 4);
  float* st_s = (float*)alloc((size_t)B_ * H_ * 4);
  float* st_c = (float*)alloc((size_t)B_ * H_ * 4);
  size_t fixed = off;

  // per-timestep chunk cost: xs2 (128*2048*2B) + drive (128*1024*4B) = 1 MiB
  size_t per_t = (size_t)128 * 2048 * 2 + (size_t)128 * 1024 * 4;
  int Tc = 1;
  if (ws_size > fixed + per_t) Tc = (int)((ws_size - fixed) / per_t);
  if (Tc > T_) Tc = T_;
  if (Tc < 1) Tc = 1;
  unsigned short* xs = (unsigned short*)alloc((size_t)128 * Tc * 2048 * 2);
  float* drive = (float*)alloc((size_t)128 * Tc * 1024 * 4);

  k_build_wt<<<dim3(8, 1024), dim3(256), 0, stream>>>(W_in, Wt);
  k_csc_count<<<dim3(64), dim3(256), 0, stream>>>(mask, cntkc);
  k_csc_fill<<<dim3(64), dim3(256), 0, stream>>>(W_rec, mask, cntkc, csc, colcnt);
  k_csc_pad<<<dim3(1), dim3(1024), 0, stream>>>(csc, colcnt, gmaxb);

  for (int t0 = 0; t0 < T_; t0 += Tc) {
    int tc = (Tc < T_ - t0) ? Tc : (T_ - t0);
    k_build_xs<<<dim3(64 * tc), dim3(256), 0, stream>>>(x, xs, t0, tc);
    k_gemm<<<dim3(tc, 4), dim3(512), 0, stream>>>(xs, Wt, drive);
    k_rsnn<<<dim3(128), dim3(1024), 0, stream>>>(drive, csc, gmaxb, h_bias, W_out, b_out,
                                                 st_v, st_s, st_c, out, t0, tc,
                                                 (t0 + tc >= T_) ? 1 : 0);
  }
}